// Round 1
// baseline (2237.821 us; speedup 1.0000x reference)
//
#include <hip/hip_runtime.h>
#include <hip/hip_bf16.h>

// Problem constants (match reference)
#define BB 512      // batch
#define DD 2048     // input dim
#define KK 4096     // code dim
#define CC 512      // cause dim
#define LR 0.001f
#define GAMMA 0.1f

typedef __attribute__((ext_vector_type(8))) short short8;
typedef __attribute__((ext_vector_type(4))) float f32x4;

__device__ __forceinline__ unsigned short f2bf(float f) {
  union { float f; unsigned u; } x; x.f = f;
  unsigned r = x.u + 0x7FFF + ((x.u >> 16) & 1);   // RNE
  return (unsigned short)(r >> 16);
}

__device__ __forceinline__ void g2l16(const void* g, void* l) {
  __builtin_amdgcn_global_load_lds(
      (const __attribute__((address_space(1))) void*)g,
      (__attribute__((address_space(3))) void*)l, 16, 0, 0);
}

// C[M,N] = A[M,Kd] @ Bm[N,Kd]^T   (both operands K-major, bf16, fp32 accumulate)
// MODE 0: z-gemm        -> p1[idx] = acc                         (z fp32)
// MODE 1: out-gemm      -> h0[idx] = bf16(acc - p0[idx])         (r = out - inputs)
// MODE 2: final out     -> p1[idx] = acc                         (d_out fp32)
// MODE 3: gradx + prox  -> p0=z, p1=x(io), h0=xb, h1=g
// MODE 4: gradu + prox  -> p1=u(io), h0=ub
template<int MODE>
__global__ __launch_bounds__(256, 2)
void gemm_bt(const unsigned short* __restrict__ A,
             const unsigned short* __restrict__ Bm,
             int M, int N, int Kd,
             const float* __restrict__ p0,
             float* __restrict__ p1,
             unsigned short* __restrict__ h0,
             unsigned short* __restrict__ h1) {
  __shared__ unsigned short As[128 * 32];
  __shared__ unsigned short Bs[128 * 32];
  const int tid = threadIdx.x;
  const int w   = tid >> 6;        // wave 0..3
  const int l   = tid & 63;
  const int bm  = blockIdx.y * 128;
  const int bn  = blockIdx.x * 128;
  const int wr  = w >> 1, wc = w & 1;     // 2x2 wave grid, 64x64 each
  const int fr  = l & 15, fq = l >> 4;    // fragment row / k-quarter
  const int srow = l >> 2, skel = (l & 3) * 8;  // staging lane mapping

  f32x4 acc[4][4];
#pragma unroll
  for (int m = 0; m < 4; m++)
#pragma unroll
    for (int n = 0; n < 4; n++) acc[m][n] = f32x4{0.f, 0.f, 0.f, 0.f};

  const int c0 = 2 * w, c1 = 2 * w + 1;  // each wave stages 2 chunks of A and B
  const unsigned short* a0 = A + (size_t)(bm + 16 * c0 + srow) * Kd + skel;
  const unsigned short* a1 = A + (size_t)(bm + 16 * c1 + srow) * Kd + skel;
  const unsigned short* b0 = Bm + (size_t)(bn + 16 * c0 + srow) * Kd + skel;
  const unsigned short* b1 = Bm + (size_t)(bn + 16 * c1 + srow) * Kd + skel;

  for (int k0 = 0; k0 < Kd; k0 += 32) {
    __syncthreads();                       // LDS free to overwrite
    g2l16(a0 + k0, As + c0 * 512);
    g2l16(a1 + k0, As + c1 * 512);
    g2l16(b0 + k0, Bs + c0 * 512);
    g2l16(b1 + k0, Bs + c1 * 512);
    __syncthreads();                       // staging drained (compiler emits vmcnt(0))

    short8 af[4], bfr[4];
#pragma unroll
    for (int m = 0; m < 4; m++)
      af[m] = *(const short8*)(As + (wr * 64 + m * 16 + fr) * 32 + fq * 8);
#pragma unroll
    for (int n = 0; n < 4; n++)
      bfr[n] = *(const short8*)(Bs + (wc * 64 + n * 16 + fr) * 32 + fq * 8);
#pragma unroll
    for (int m = 0; m < 4; m++)
#pragma unroll
      for (int n = 0; n < 4; n++)
        acc[m][n] = __builtin_amdgcn_mfma_f32_16x16x32_bf16(af[m], bfr[n], acc[m][n], 0, 0, 0);
  }

  // Epilogue. C/D layout: col = lane&15, row = (lane>>4)*4 + j  [m89-verified]
#pragma unroll
  for (int m = 0; m < 4; m++) {
#pragma unroll
    for (int n = 0; n < 4; n++) {
#pragma unroll
      for (int j = 0; j < 4; j++) {
        const int row = bm + wr * 64 + m * 16 + fq * 4 + j;
        const int col = bn + wc * 64 + n * 16 + fr;
        const size_t idx = (size_t)row * N + col;
        const float v = acc[m][n][j];
        if constexpr (MODE == 0) {
          p1[idx] = v;
        } else if constexpr (MODE == 1) {
          h0[idx] = f2bf(v - p0[idx]);
        } else if constexpr (MODE == 2) {
          p1[idx] = v;
        } else if constexpr (MODE == 3) {
          const float zv = p0[idx];
          const float e = __expf(-zv);
          const float thr = (LR * GAMMA * 0.5f) * (1.0f + e);
          const float xv = p1[idx] - (2.0f * LR) * v;
          const float xn = fmaxf(xv - thr, 0.f) + fminf(xv + thr, 0.f);
          p1[idx] = xn;
          h0[idx] = f2bf(xn);
          h1[idx] = f2bf((-0.5f * GAMMA) * e * fabsf(xn));
        } else {  // MODE 4
          const float uv = p1[idx];
          const float gu = v + (0.02f * GAMMA) * uv;
          const float uu = uv - LR * gu;
          const float un = fmaxf(uu - (LR * GAMMA), 0.f) + fminf(uu + (LR * GAMMA), 0.f);
          p1[idx] = un;
          h0[idx] = f2bf(un);
        }
      }
    }
  }
}

// dst[c*R + r] = bf16(src[r*C + c]);  R,C multiples of 64
__global__ __launch_bounds__(256)
void transpose_f32_bf16(const float* __restrict__ src, unsigned short* __restrict__ dst,
                        int R, int C) {
  __shared__ float tile[64][65];
  const int tid = threadIdx.x;
  const int tr = blockIdx.y * 64;
  const int tc = blockIdx.x * 64;
  const int lr = tid >> 4;          // 0..15
  const int lc = (tid & 15) * 4;    // 0,4,...,60
#pragma unroll
  for (int i = 0; i < 4; i++) {
    const float4 v = *(const float4*)(src + (size_t)(tr + lr + 16 * i) * C + tc + lc);
    tile[lr + 16 * i][lc + 0] = v.x;
    tile[lr + 16 * i][lc + 1] = v.y;
    tile[lr + 16 * i][lc + 2] = v.z;
    tile[lr + 16 * i][lc + 3] = v.w;
  }
  __syncthreads();
#pragma unroll
  for (int j = 0; j < 16; j++) {
    const int idx = tid + j * 256;
    const int c = idx >> 6;
    const int r = idx & 63;
    dst[(size_t)(tc + c) * R + tr + r] = f2bf(tile[r][c]);
  }
}

__global__ void convert_bf16_k(const float* __restrict__ src, unsigned short* __restrict__ dst, int n4) {
  const int i = blockIdx.x * blockDim.x + threadIdx.x;
  if (i < n4) {
    const float4 v = ((const float4*)src)[i];
    const unsigned lo = (unsigned)f2bf(v.x) | ((unsigned)f2bf(v.y) << 16);
    const unsigned hi = (unsigned)f2bf(v.z) | ((unsigned)f2bf(v.w) << 16);
    ((uint2*)dst)[i] = uint2{lo, hi};
  }
}

__global__ void zero_k(unsigned int* p, int n) {
  const int i = blockIdx.x * blockDim.x + threadIdx.x;
  if (i < n) p[i] = 0u;
}

__global__ void initu_k(const float* __restrict__ u0, float* __restrict__ u,
                        unsigned short* __restrict__ ub, int n) {
  const int i = blockIdx.x * blockDim.x + threadIdx.x;
  if (i < n) {
    const float v = u0[i];
    u[i] = v;
    ub[i] = f2bf(v);
  }
}

extern "C" void kernel_launch(void* const* d_in, const int* in_sizes, int n_in,
                              void* d_out, int out_size, void* d_ws, size_t ws_size,
                              hipStream_t stream) {
  const float* inputs = (const float*)d_in[0];   // (BB, DD)
  const float* W      = (const float*)d_in[1];   // (KK, DD)
  const float* V      = (const float*)d_in[2];   // (CC, KK)
  const float* u0     = (const float*)d_in[3];   // (BB, CC)
  float* out = (float*)d_out;                    // (BB, DD)

  char* ws = (char*)d_ws;
  size_t off = 0;
  auto alloc = [&](size_t bytes) -> void* {
    void* p = ws + off;
    off += (bytes + 255) & ~(size_t)255;
    return p;
  };
  unsigned short* Wb = (unsigned short*)alloc((size_t)KK * DD * 2);  // W  (KK,DD) bf16
  unsigned short* Wt = (unsigned short*)alloc((size_t)DD * KK * 2);  // W^T (DD,KK) bf16
  unsigned short* Vb = (unsigned short*)alloc((size_t)CC * KK * 2);  // V  (CC,KK) bf16
  unsigned short* Vt = (unsigned short*)alloc((size_t)KK * CC * 2);  // V^T (KK,CC) bf16
  unsigned short* xb = (unsigned short*)alloc((size_t)BB * KK * 2);  // x bf16
  unsigned short* g  = (unsigned short*)alloc((size_t)BB * KK * 2);  // dcost_dz bf16
  unsigned short* r  = (unsigned short*)alloc((size_t)BB * DD * 2);  // out-inputs bf16
  unsigned short* ub = (unsigned short*)alloc((size_t)BB * CC * 2);  // u bf16
  float* x = (float*)alloc((size_t)BB * KK * 4);
  float* z = (float*)alloc((size_t)BB * KK * 4);
  float* u = (float*)alloc((size_t)BB * CC * 4);

  // one-time (per launch) conversions
  convert_bf16_k<<<(KK * DD / 4 + 255) / 256, 256, 0, stream>>>(W, Wb, KK * DD / 4);
  transpose_f32_bf16<<<dim3(DD / 64, KK / 64), 256, 0, stream>>>(W, Wt, KK, DD);
  convert_bf16_k<<<(CC * KK / 4 + 255) / 256, 256, 0, stream>>>(V, Vb, CC * KK / 4);
  transpose_f32_bf16<<<dim3(KK / 64, CC / 64), 256, 0, stream>>>(V, Vt, CC, KK);
  zero_k<<<(BB * KK / 2 + 255) / 256, 256, 0, stream>>>((unsigned int*)xb, BB * KK / 2);
  zero_k<<<(BB * KK + 255) / 256, 256, 0, stream>>>((unsigned int*)x, BB * KK);
  initu_k<<<(BB * CC + 255) / 256, 256, 0, stream>>>(u0, u, ub, BB * CC);

  for (int t = 0; t < 10; t++) {
    if (t < 9) {
      // out = x@W ; r = bf16(out - inputs)
      gemm_bt<1><<<dim3(DD / 128, BB / 128), 256, 0, stream>>>(xb, Wt, BB, DD, KK,
                                                               inputs, nullptr, r, nullptr);
      // z = u@V
      gemm_bt<0><<<dim3(KK / 128, BB / 128), 256, 0, stream>>>(ub, Vt, BB, KK, CC,
                                                               nullptr, z, nullptr, nullptr);
      // grad_x = 2*r@W^T ; x = prox(x - LR*grad_x, LR*GAMMA*causes(z)); g = -0.5*exp(-z)*|x|*GAMMA
      gemm_bt<3><<<dim3(KK / 128, BB / 128), 256, 0, stream>>>(r, Wb, BB, KK, DD,
                                                               z, x, xb, g);
      // grad_u = g@V^T + 0.02*GAMMA*u ; u = prox(u - LR*grad_u, LR*GAMMA)
      gemm_bt<4><<<dim3(CC / 128, BB / 128), 256, 0, stream>>>(g, Vb, BB, CC, KK,
                                                               nullptr, u, ub, nullptr);
    } else {
      // final: d_out = x@W (fp32)
      gemm_bt<2><<<dim3(DD / 128, BB / 128), 256, 0, stream>>>(xb, Wt, BB, DD, KK,
                                                               nullptr, out, nullptr, nullptr);
    }
  }
}

// Round 2
// 736.226 us; speedup vs baseline: 3.0396x; 3.0396x over previous
//
#include <hip/hip_runtime.h>
#include <hip/hip_bf16.h>

// Problem constants (match reference)
#define BB 512      // batch
#define DD 2048     // input dim
#define KK 4096     // code dim
#define CC 512      // cause dim
#define LR 0.001f
#define GAMMA 0.1f

typedef __attribute__((ext_vector_type(8))) short short8;
typedef __attribute__((ext_vector_type(4))) float f32x4;

__device__ __forceinline__ unsigned short f2bf(float f) {
  union { float f; unsigned u; } x; x.f = f;
  unsigned r = x.u + 0x7FFF + ((x.u >> 16) & 1);   // RNE
  return (unsigned short)(r >> 16);
}

__device__ __forceinline__ void g2l16(const void* g, void* l) {
  __builtin_amdgcn_global_load_lds(
      (const __attribute__((address_space(1))) void*)g,
      (__attribute__((address_space(3))) void*)l, 16, 0, 0);
}

// Partial GEMM: p1[bz*M*N + i] = A[M, kbase:kbase+kslice] @ Bm[N, same]^T
// Both operands K-major bf16, fp32 accumulate. 128x128 tile, BK=64,
// LDS XOR-swizzled (st-16-style): data(row, colbyte cb) stored at
// row*128 + (cb ^ ((row&7)<<4)). global_load_lds writes linearly, so the
// global SOURCE is pre-swizzled (rule #21) and ds_read applies the XOR.
__global__ __launch_bounds__(256, 2)
void gemm_sk(const unsigned short* __restrict__ A,
             const unsigned short* __restrict__ Bm,
             int M, int N, int Kd, int kslice,
             float* __restrict__ p1) {
  __shared__ unsigned short As[128 * 64];   // 16 KB
  __shared__ unsigned short Bs[128 * 64];   // 16 KB
  const int tid = threadIdx.x;
  const int w   = tid >> 6;        // wave 0..3
  const int l   = tid & 63;
  const int bm  = blockIdx.y * 128;
  const int bn  = blockIdx.x * 128;
  const int kbase = blockIdx.z * kslice;
  const int wr  = w >> 1, wc = w & 1;     // 2x2 wave grid, 64x64 each
  const int fr  = l & 15, fq = l >> 4;    // fragment row / k-quarter

  f32x4 acc[4][4];
#pragma unroll
  for (int m = 0; m < 4; m++)
#pragma unroll
    for (int n = 0; n < 4; n++) acc[m][n] = f32x4{0.f, 0.f, 0.f, 0.f};

  // Staging: 4 calls/matrix/iter, each covers 32 rows (wave does 8 rows).
  // Lane l: row = c*32 + w*8 + (l>>3); src col pre-swizzled so linear LDS
  // dest realizes the XOR layout (row&7 == l>>3 here).
  const int srow = w * 8 + (l >> 3);
  const int scol = 8 * ((l & 7) ^ (l >> 3));
  const unsigned short* ag = A  + (size_t)(bm + srow) * Kd + kbase + scol;
  const unsigned short* bg = Bm + (size_t)(bn + srow) * Kd + kbase + scol;
  const int lbase = w * 8 * 64;            // wave-uniform LDS elem offset

  // ds_read byte offsets (XOR swizzle applied; addr^64 selects kk half)
  const int xa = ((fq * 16) ^ ((fr & 7) << 4));

  for (int k0 = 0; k0 < kslice; k0 += 64) {
    __syncthreads();
#pragma unroll
    for (int c = 0; c < 4; c++) {
      g2l16(ag + (size_t)c * 32 * Kd + k0, As + lbase + c * 2048);
      g2l16(bg + (size_t)c * 32 * Kd + k0, Bs + lbase + c * 2048);
    }
    __syncthreads();

#pragma unroll
    for (int kk = 0; kk < 2; kk++) {
      short8 af[4], bf[4];
#pragma unroll
      for (int m = 0; m < 4; m++) {
        const int row = wr * 64 + m * 16 + fr;
        af[m] = *(const short8*)((const char*)As + row * 128 + ((kk * 64 + fq * 16) ^ ((fr & 7) << 4)));
      }
#pragma unroll
      for (int n = 0; n < 4; n++) {
        const int row = wc * 64 + n * 16 + fr;
        bf[n] = *(const short8*)((const char*)Bs + row * 128 + ((kk * 64 + fq * 16) ^ ((fr & 7) << 4)));
      }
#pragma unroll
      for (int m = 0; m < 4; m++)
#pragma unroll
        for (int n = 0; n < 4; n++)
          acc[m][n] = __builtin_amdgcn_mfma_f32_16x16x32_bf16(af[m], bf[n], acc[m][n], 0, 0, 0);
    }
  }

  float* dst = p1 + (size_t)blockIdx.z * M * N;
  (void)xa;
#pragma unroll
  for (int m = 0; m < 4; m++)
#pragma unroll
    for (int n = 0; n < 4; n++)
#pragma unroll
      for (int j = 0; j < 4; j++) {
        const int row = bm + wr * 64 + m * 16 + fq * 4 + j;
        const int col = bn + wc * 64 + n * 16 + fr;
        dst[(size_t)row * N + col] = acc[m][n][j];
      }
}

// ---- fused elementwise epilogues (float4-vectorized) ----

__device__ __forceinline__ void store4bf(unsigned short* p, f32x4 v) {
  const unsigned lo = (unsigned)f2bf(v[0]) | ((unsigned)f2bf(v[1]) << 16);
  const unsigned hi = (unsigned)f2bf(v[2]) | ((unsigned)f2bf(v[3]) << 16);
  *(uint2*)p = uint2{lo, hi};
}

// r = bf16(sum(part[0..7]) - inputs)      over BB*DD
__global__ __launch_bounds__(256) void ep_r_k(const float* __restrict__ part,
                                              const float* __restrict__ inputs,
                                              unsigned short* __restrict__ r) {
  const int i = blockIdx.x * 256 + threadIdx.x;
  f32x4 s = f32x4{0.f, 0.f, 0.f, 0.f};
#pragma unroll
  for (int k = 0; k < 8; k++) s += ((const f32x4*)(part + (size_t)k * BB * DD))[i];
  const f32x4 in = ((const f32x4*)inputs)[i];
  store4bf(r + (size_t)i * 4, s - in);
}

// out = sum(part[0..7])  (fp32, final step)
__global__ __launch_bounds__(256) void ep_out_k(const float* __restrict__ part,
                                                float* __restrict__ out) {
  const int i = blockIdx.x * 256 + threadIdx.x;
  f32x4 s = f32x4{0.f, 0.f, 0.f, 0.f};
#pragma unroll
  for (int k = 0; k < 8; k++) s += ((const f32x4*)(part + (size_t)k * BB * DD))[i];
  ((f32x4*)out)[i] = s;
}

// x-update: v = sum(part[0..3]) (= r@W^T); prox; writes x, xb, g    over BB*KK
__global__ __launch_bounds__(256) void ep_x_k(const float* __restrict__ part,
                                              const float* __restrict__ z,
                                              float* __restrict__ x,
                                              unsigned short* __restrict__ xb,
                                              unsigned short* __restrict__ g) {
  const int i = blockIdx.x * 256 + threadIdx.x;
  f32x4 v = f32x4{0.f, 0.f, 0.f, 0.f};
#pragma unroll
  for (int k = 0; k < 4; k++) v += ((const f32x4*)(part + (size_t)k * BB * KK))[i];
  const f32x4 zv = ((const f32x4*)z)[i];
  const f32x4 xo = ((const f32x4*)x)[i];
  f32x4 xn, gg;
#pragma unroll
  for (int j = 0; j < 4; j++) {
    const float e = __expf(-zv[j]);
    const float thr = (LR * GAMMA * 0.5f) * (1.0f + e);      // lr*gamma*causes
    const float xv = xo[j] - (2.0f * LR) * v[j];
    const float t = fmaxf(xv - thr, 0.f) + fminf(xv + thr, 0.f);
    xn[j] = t;
    gg[j] = (-0.5f * GAMMA) * e * fabsf(t);
  }
  ((f32x4*)x)[i] = xn;
  store4bf(xb + (size_t)i * 4, xn);
  store4bf(g + (size_t)i * 4, gg);
}

// u-update: gu = sum(part[0..15]) + 0.02*GAMMA*u; prox; writes u, ub   over BB*CC
__global__ __launch_bounds__(256) void ep_u_k(const float* __restrict__ part,
                                              float* __restrict__ u,
                                              unsigned short* __restrict__ ub) {
  const int i = blockIdx.x * 256 + threadIdx.x;
  f32x4 v = f32x4{0.f, 0.f, 0.f, 0.f};
#pragma unroll
  for (int k = 0; k < 16; k++) v += ((const f32x4*)(part + (size_t)k * BB * CC))[i];
  const f32x4 uo = ((const f32x4*)u)[i];
  f32x4 un;
#pragma unroll
  for (int j = 0; j < 4; j++) {
    const float gu = v[j] + (0.02f * GAMMA) * uo[j];
    const float uu = uo[j] - LR * gu;
    un[j] = fmaxf(uu - (LR * GAMMA), 0.f) + fminf(uu + (LR * GAMMA), 0.f);
  }
  ((f32x4*)u)[i] = un;
  store4bf(ub + (size_t)i * 4, un);
}

// ---- one-time conversion / init kernels ----

__global__ __launch_bounds__(256)
void transpose_f32_bf16(const float* __restrict__ src, unsigned short* __restrict__ dst,
                        int R, int C) {
  __shared__ float tile[64][65];
  const int tid = threadIdx.x;
  const int tr = blockIdx.y * 64;
  const int tc = blockIdx.x * 64;
  const int lr = tid >> 4;
  const int lc = (tid & 15) * 4;
#pragma unroll
  for (int i = 0; i < 4; i++) {
    const float4 v = *(const float4*)(src + (size_t)(tr + lr + 16 * i) * C + tc + lc);
    tile[lr + 16 * i][lc + 0] = v.x;
    tile[lr + 16 * i][lc + 1] = v.y;
    tile[lr + 16 * i][lc + 2] = v.z;
    tile[lr + 16 * i][lc + 3] = v.w;
  }
  __syncthreads();
#pragma unroll
  for (int j = 0; j < 16; j++) {
    const int idx = tid + j * 256;
    const int c = idx >> 6;
    const int r = idx & 63;
    dst[(size_t)(tc + c) * R + tr + r] = f2bf(tile[r][c]);
  }
}

__global__ void convert_bf16_k(const float* __restrict__ src, unsigned short* __restrict__ dst, int n4) {
  const int i = blockIdx.x * blockDim.x + threadIdx.x;
  if (i < n4) {
    const float4 v = ((const float4*)src)[i];
    const unsigned lo = (unsigned)f2bf(v.x) | ((unsigned)f2bf(v.y) << 16);
    const unsigned hi = (unsigned)f2bf(v.z) | ((unsigned)f2bf(v.w) << 16);
    ((uint2*)dst)[i] = uint2{lo, hi};
  }
}

__global__ void zero_k(unsigned int* p, int n) {
  const int i = blockIdx.x * blockDim.x + threadIdx.x;
  if (i < n) p[i] = 0u;
}

__global__ void initu_k(const float* __restrict__ u0, float* __restrict__ u,
                        unsigned short* __restrict__ ub, int n) {
  const int i = blockIdx.x * blockDim.x + threadIdx.x;
  if (i < n) {
    const float v = u0[i];
    u[i] = v;
    ub[i] = f2bf(v);
  }
}

extern "C" void kernel_launch(void* const* d_in, const int* in_sizes, int n_in,
                              void* d_out, int out_size, void* d_ws, size_t ws_size,
                              hipStream_t stream) {
  const float* inputs = (const float*)d_in[0];   // (BB, DD)
  const float* W      = (const float*)d_in[1];   // (KK, DD)
  const float* V      = (const float*)d_in[2];   // (CC, KK)
  const float* u0     = (const float*)d_in[3];   // (BB, CC)
  float* out = (float*)d_out;                    // (BB, DD)

  char* ws = (char*)d_ws;
  size_t off = 0;
  auto alloc = [&](size_t bytes) -> void* {
    void* p = ws + off;
    off += (bytes + 255) & ~(size_t)255;
    return p;
  };
  unsigned short* Wb = (unsigned short*)alloc((size_t)KK * DD * 2);  // W  (KK,DD) bf16
  unsigned short* Wt = (unsigned short*)alloc((size_t)DD * KK * 2);  // W^T (DD,KK) bf16
  unsigned short* Vb = (unsigned short*)alloc((size_t)CC * KK * 2);  // V  (CC,KK) bf16
  unsigned short* Vt = (unsigned short*)alloc((size_t)KK * CC * 2);  // V^T (KK,CC) bf16
  unsigned short* xb = (unsigned short*)alloc((size_t)BB * KK * 2);  // x bf16
  unsigned short* g  = (unsigned short*)alloc((size_t)BB * KK * 2);  // dcost_dz bf16
  unsigned short* r  = (unsigned short*)alloc((size_t)BB * DD * 2);  // out-inputs bf16
  unsigned short* ub = (unsigned short*)alloc((size_t)BB * CC * 2);  // u bf16
  float* x = (float*)alloc((size_t)BB * KK * 4);
  float* z = (float*)alloc((size_t)BB * KK * 4);
  float* u = (float*)alloc((size_t)BB * CC * 4);
  float* part = (float*)alloc((size_t)32 * 1024 * 1024);  // split-K partials arena

  // one-time (per launch) conversions
  convert_bf16_k<<<(KK * DD / 4 + 255) / 256, 256, 0, stream>>>(W, Wb, KK * DD / 4);
  transpose_f32_bf16<<<dim3(DD / 64, KK / 64), 256, 0, stream>>>(W, Wt, KK, DD);
  convert_bf16_k<<<(CC * KK / 4 + 255) / 256, 256, 0, stream>>>(V, Vb, CC * KK / 4);
  transpose_f32_bf16<<<dim3(KK / 64, CC / 64), 256, 0, stream>>>(V, Vt, CC, KK);
  zero_k<<<(BB * KK / 2 + 255) / 256, 256, 0, stream>>>((unsigned int*)xb, BB * KK / 2);
  zero_k<<<(BB * KK + 255) / 256, 256, 0, stream>>>((unsigned int*)x, BB * KK);
  initu_k<<<(BB * CC + 255) / 256, 256, 0, stream>>>(u0, u, ub, BB * CC);

  for (int t = 0; t < 10; t++) {
    // out-partials: x@W, split-K=8 (Kslice 512) -> 512 wgs
    gemm_sk<<<dim3(DD / 128, BB / 128, 8), 256, 0, stream>>>(xb, Wt, BB, DD, KK, KK / 8, part);
    if (t < 9) {
      // r = bf16(out - inputs)
      ep_r_k<<<BB * DD / 4 / 256, 256, 0, stream>>>(part, inputs, r);
      // z = u@V  (direct store: splitK=1, grid 128)
      gemm_sk<<<dim3(KK / 128, BB / 128, 1), 256, 0, stream>>>(ub, Vt, BB, KK, CC, CC, z);
      // gradx partials: r@W^T, split-K=4 (Kslice 512) -> 512 wgs
      gemm_sk<<<dim3(KK / 128, BB / 128, 4), 256, 0, stream>>>(r, Wb, BB, KK, DD, DD / 4, part);
      // x prox update
      ep_x_k<<<BB * KK / 4 / 256, 256, 0, stream>>>(part, z, x, xb, g);
      // gradu partials: g@V^T, split-K=16 (Kslice 256) -> 256 wgs
      gemm_sk<<<dim3(CC / 128, BB / 128, 16), 256, 0, stream>>>(g, Vb, BB, CC, KK, KK / 16, part);
      // u prox update
      ep_u_k<<<BB * CC / 4 / 256, 256, 0, stream>>>(part, u, ub);
    } else {
      // final: d_out = sum of out-partials (fp32)
      ep_out_k<<<BB * DD / 4 / 256, 256, 0, stream>>>(part, out);
    }
  }
}